// Round 3
// baseline (639.303 us; speedup 1.0000x reference)
//
#include <hip/hip_runtime.h>
#include <cstddef>
#include <cstdint>

#define TMAX 512
#define HDIM 64

typedef _Float16 half2v __attribute__((ext_vector_type(2)));

__device__ __forceinline__ float fsig(float x) {
    x = fminf(fmaxf(x, -30.f), 30.f);
    float e = __expf(-x);
    return __builtin_amdgcn_rcpf(1.f + e);
}
__device__ __forceinline__ float ftanh(float x) {
    x = fminf(fmaxf(x, -15.f), 15.f);      // tanh(15)==1 in fp32; avoid inf/inf
    float e = __expf(2.f * x);
    return (e - 1.f) * __builtin_amdgcn_rcpf(e + 1.f);
}

#if __has_builtin(__builtin_amdgcn_fdot2)
__device__ __forceinline__ float dot2acc(half2v a, half2v b, float c) {
    return __builtin_amdgcn_fdot2(a, b, c, false);   // v_dot2_f32_f16
}
#else
__device__ __forceinline__ float dot2acc(half2v a, half2v b, float c) {
    return fmaf((float)a.y, (float)b.y, fmaf((float)a.x, (float)b.x, c));
}
#endif

// One wave (64 lanes) per batch row. Lane u owns hidden unit u and computes
// gates u, u+64, u+128, u+192. No __syncthreads anywhere. Weights live in
// VGPRs, pinned by opaque asm so the compiler can't rematerialize the
// global loads + f32->f16 conversion inside the step loops (round-2 bug:
// VGPR_Count=96 proved w2 was being reloaded+converted every step).
__global__ __launch_bounds__(64, 2)
void lstm_wave_kernel(const float* __restrict__ ctx_g,   // (B, T)
                      const float* __restrict__ Wih_e,   // (256,1)
                      const float* __restrict__ Whh_e,   // (256,64)
                      const float* __restrict__ bih_e,
                      const float* __restrict__ bhh_e,
                      const float* __restrict__ Wih_d,
                      const float* __restrict__ Whh_d,
                      const float* __restrict__ bih_d,
                      const float* __restrict__ bhh_d,
                      const float* __restrict__ Whead,   // (1,64)
                      const float* __restrict__ bhead,   // (1,)
                      float* __restrict__ out,           // (B, n_steps)
                      int T, int n_steps)
{
    __shared__ __align__(16) float    ctx_s[TMAX];
    __shared__ __align__(16) _Float16 h_s[HDIM];

    const int lane = threadIdx.x;           // 0..63 == hidden unit
    const int row  = blockIdx.x;            // batch row

    const float* ctxr = ctx_g + (size_t)row * T;
    for (int t = lane; t < T; t += 64) ctx_s[t] = ctxr[t];

    uint32_t wbits[4][32];                   // fp16-packed W_hh rows, 128 VGPRs
    float    wih[4], bias[4];

    // ---- fill + PIN encoder weights ----
    #pragma unroll
    for (int g = 0; g < 4; ++g) {
        const int j = lane + (g << 6);
        const float2* wr = reinterpret_cast<const float2*>(Whh_e + (size_t)j * HDIM);
        #pragma unroll
        for (int k = 0; k < 32; ++k) {
            float2 wv = wr[k];
            half2v hw = half2v{(_Float16)wv.x, (_Float16)wv.y};
            wbits[g][k] = __builtin_bit_cast(uint32_t, hw);
        }
        wih[g]  = Wih_e[j];
        bias[g] = bih_e[j] + bhh_e[j];
    }
    #pragma unroll
    for (int g = 0; g < 4; ++g) {
        #pragma unroll
        for (int k = 0; k < 32; ++k) asm volatile("" : "+v"(wbits[g][k]));
        asm volatile("" : "+v"(wih[g]), "+v"(bias[g]));
    }

    float c = 0.f, h = 0.f;
    h_s[lane] = (_Float16)0.f;

    // ---------------- encoder: T sequential steps ----------------
    for (int t = 0; t < T; ++t) {
        const float x = ctx_s[t];
        // two partial chains per gate (halve dep-chain depth)
        float aA[4], aB[4];
        #pragma unroll
        for (int g = 0; g < 4; ++g) { aA[g] = fmaf(x, wih[g], bias[g]); aB[g] = 0.f; }
        #pragma unroll
        for (int ch = 0; ch < 8; ++ch) {     // 8 x ds_read_b128 (broadcast)
            uint4 hv = reinterpret_cast<const uint4*>(h_s)[ch];
            half2v hp[4];
            hp[0] = __builtin_bit_cast(half2v, hv.x);
            hp[1] = __builtin_bit_cast(half2v, hv.y);
            hp[2] = __builtin_bit_cast(half2v, hv.z);
            hp[3] = __builtin_bit_cast(half2v, hv.w);
            #pragma unroll
            for (int e = 0; e < 4; ++e) {
                const int k = ch * 4 + e;
                #pragma unroll
                for (int g = 0; g < 4; ++g) {
                    half2v wv = __builtin_bit_cast(half2v, wbits[g][k]);
                    if (ch < 4) aA[g] = dot2acc(wv, hp[e], aA[g]);
                    else        aB[g] = dot2acc(wv, hp[e], aB[g]);
                }
            }
        }
        const float ig = fsig(aA[0] + aB[0]);
        const float fg = fsig(aA[1] + aB[1]);
        const float gg = ftanh(aA[2] + aB[2]);
        const float og = fsig(aA[3] + aB[3]);
        c = fmaf(fg, c, ig * gg);
        h = og * ftanh(c);
        h_s[lane] = (_Float16)h;             // visible to the wave next step
    }

    // ---- fill + PIN decoder weights ----
    #pragma unroll
    for (int g = 0; g < 4; ++g) {
        const int j = lane + (g << 6);
        const float2* wr = reinterpret_cast<const float2*>(Whh_d + (size_t)j * HDIM);
        #pragma unroll
        for (int k = 0; k < 32; ++k) {
            float2 wv = wr[k];
            half2v hw = half2v{(_Float16)wv.x, (_Float16)wv.y};
            wbits[g][k] = __builtin_bit_cast(uint32_t, hw);
        }
        wih[g]  = Wih_d[j];
        bias[g] = bih_d[j] + bhh_d[j];
    }
    #pragma unroll
    for (int g = 0; g < 4; ++g) {
        #pragma unroll
        for (int k = 0; k < 32; ++k) asm volatile("" : "+v"(wbits[g][k]));
        asm volatile("" : "+v"(wih[g]), "+v"(bias[g]));
    }
    const float wh = Whead[lane];
    const float bh = bhead[0];
    float z = ctx_s[T - 1];                  // z0 = context[:, -1]

    // ---------------- decoder: n_steps sequential steps ----------------
    for (int s = 0; s < n_steps; ++s) {
        float aA[4], aB[4];
        #pragma unroll
        for (int g = 0; g < 4; ++g) { aA[g] = fmaf(z, wih[g], bias[g]); aB[g] = 0.f; }
        #pragma unroll
        for (int ch = 0; ch < 8; ++ch) {
            uint4 hv = reinterpret_cast<const uint4*>(h_s)[ch];
            half2v hp[4];
            hp[0] = __builtin_bit_cast(half2v, hv.x);
            hp[1] = __builtin_bit_cast(half2v, hv.y);
            hp[2] = __builtin_bit_cast(half2v, hv.z);
            hp[3] = __builtin_bit_cast(half2v, hv.w);
            #pragma unroll
            for (int e = 0; e < 4; ++e) {
                const int k = ch * 4 + e;
                #pragma unroll
                for (int g = 0; g < 4; ++g) {
                    half2v wv = __builtin_bit_cast(half2v, wbits[g][k]);
                    if (ch < 4) aA[g] = dot2acc(wv, hp[e], aA[g]);
                    else        aB[g] = dot2acc(wv, hp[e], aB[g]);
                }
            }
        }
        const float ig = fsig(aA[0] + aB[0]);
        const float fg = fsig(aA[1] + aB[1]);
        const float gg = ftanh(aA[2] + aB[2]);
        const float og = fsig(aA[3] + aB[3]);
        c = fmaf(fg, c, ig * gg);
        h = og * ftanh(c);
        h_s[lane] = (_Float16)h;

        // head: z = sum_u h[u]*Whead[u] + b (fp32 butterfly, wave-uniform z)
        float p = h * wh;
        #pragma unroll
        for (int off = 32; off >= 1; off >>= 1)
            p += __shfl_xor(p, off);
        z = p + bh;
        if (lane == 0) out[(size_t)row * n_steps + s] = z;
    }
}

extern "C" void kernel_launch(void* const* d_in, const int* in_sizes, int n_in,
                              void* d_out, int out_size, void* d_ws, size_t ws_size,
                              hipStream_t stream)
{
    const float* ctx   = (const float*)d_in[0];
    const float* Wih_e = (const float*)d_in[1];
    const float* Whh_e = (const float*)d_in[2];
    const float* bih_e = (const float*)d_in[3];
    const float* bhh_e = (const float*)d_in[4];
    const float* Wih_d = (const float*)d_in[5];
    const float* Whh_d = (const float*)d_in[6];
    const float* bih_d = (const float*)d_in[7];
    const float* bhh_d = (const float*)d_in[8];
    const float* Whead = (const float*)d_in[9];
    const float* bhead = (const float*)d_in[10];
    float* out = (float*)d_out;

    const int B = 2048;                 // fixed by the harness setup
    const int T = in_sizes[0] / B;      // 512
    const int n_steps = out_size / B;   // 256

    lstm_wave_kernel<<<dim3(B), dim3(64), 0, stream>>>(
        ctx, Wih_e, Whh_e, bih_e, bhh_e,
        Wih_d, Whh_d, bih_d, bhh_d,
        Whead, bhead, out, T, n_steps);
}